// Round 5
// baseline (264.297 us; speedup 1.0000x reference)
//
#include <hip/hip_runtime.h>
#include <math.h>

// GCN 2-layer, N=100000, E=3200000, feats 2->16->2.
// R12: decoupled gather/scatter. R11 post-mortem: aggc stuck at 46us with
// VALU 2%, HBM 6%, conflicts 0, occ 42% -> per-block serial chain
// (load -> divergent gather -> LDS atomic -> barrier) is the limiter, not
// wave supply. Split each aggregation:
//   k_gath: stream slotsC, gather vals[src], write msg[e] coalesced.
//           NO LDS/barriers/atomics -> pure max-MLP gather engine.
//   k_scat: stream slotsC+msg (coalesced), LDS accumulate, write partials.
//           NO gathers -> pure streaming.
// +51MB msg traffic/layer pair (~8us HBM) vs breaking the 46us chain.
// Diagnostic: if k_gath alone ~40us at high occ, divergent-gather service
// rate is the chip ceiling -> next step is src-sorted edges.
// degPart aliases partX (deg consumed by k_dinv before scat writes partials).

constexpr int N = 100000;
constexpr int LOGCB = 10;
constexpr int CB = 1 << LOGCB;   // 1024 nodes per bucket
constexpr int NC = 98;           // buckets (dst>>10)
constexpr int CAP1 = 35008;      // cap: mean 32653 + ~12 sigma (64-mult)

constexpr int B1 = 512;          // pass1 block
constexpr int EC1 = 8192;        // pass1 edges/chunk
constexpr int EPT1 = EC1 / B1;   // 16

constexpr int BA = 256;          // walk block (deg/gath/scat)
constexpr int ECA = 2048;        // walk edges/chunk
constexpr int EPTA = ECA / BA;   // 8
constexpr int MAXCH = (CAP1 + ECA - 1) / ECA;  // 18 chunks per bucket

__global__ __launch_bounds__(B1) void k_pass1(const int* __restrict__ src,
                                              const int* __restrict__ dst, int E,
                                              int* __restrict__ gfill1,
                                              int* __restrict__ slotsC) {
    __shared__ int hist[NC];
    __shared__ int base[NC];
    int t = threadIdx.x;
    if (t < NC) hist[t] = 0;
    __syncthreads();
    int s[EPT1], d[EPT1];
    int ebase = blockIdx.x * EC1 + t * EPT1;
#pragma unroll
    for (int k = 0; k < EPT1 / 4; k++) {
        int idx = ebase + 4 * k;
        if (idx + 3 < E) {
            *(int4*)(s + 4 * k) = *(const int4*)(src + idx);
            *(int4*)(d + 4 * k) = *(const int4*)(dst + idx);
        } else {
            for (int j = 0; j < 4; j++) {
                s[4 * k + j] = (idx + j < E) ? src[idx + j] : -1;
                d[4 * k + j] = (idx + j < E) ? dst[idx + j] : -1;
            }
        }
    }
#pragma unroll
    for (int k = 0; k < EPT1; k++)
        if (d[k] >= 0) atomicAdd(&hist[d[k] >> LOGCB], 1);
    __syncthreads();
    if (t < NC) {
        int c = hist[t];
        base[t] = c ? atomicAdd(&gfill1[t], c) : 0;  // device reservation atomic
        hist[t] = 0;                                  // reuse as cursor
    }
    __syncthreads();
#pragma unroll
    for (int k = 0; k < EPT1; k++) {
        if (d[k] >= 0) {
            int bin = d[k] >> LOGCB;
            int r = atomicAdd(&hist[bin], 1);  // LDS
            int pos = base[bin] + r;
            if (pos < CAP1) slotsC[bin * CAP1 + pos] = (s[k] << LOGCB) | (d[k] & (CB - 1));
        }
    }
}

// per-(bucket,chunk) degree histogram -> coalesced non-atomic partials
__global__ __launch_bounds__(BA) void k_deg(const int* __restrict__ gfill1,
                                            const int* __restrict__ slotsC,
                                            int* __restrict__ degPart) {
    __shared__ int dh[CB];
    int c = blockIdx.x / MAXCH, j = blockIdx.x % MAXCH;
    int fill = min(gfill1[c], CAP1);
    int e0 = j * ECA;
    if (e0 >= fill) return;  // uniform per block, before any sync
    int e1 = min(fill, e0 + ECA);
    int t = threadIdx.x;
    for (int i = t; i < CB; i += BA) dh[i] = 0;
    __syncthreads();
    const int* row = slotsC + c * CAP1;
    int v[EPTA];
    int ebase = e0 + t * EPTA;
#pragma unroll
    for (int k = 0; k < EPTA / 4; k++) {
        int idx = ebase + 4 * k;
        if (idx + 3 < e1) {
            *(int4*)(v + 4 * k) = *(const int4*)(row + idx);
        } else {
            for (int jj = 0; jj < 4; jj++) v[4 * k + jj] = (idx + jj < e1) ? row[idx + jj] : -1;
        }
    }
#pragma unroll
    for (int k = 0; k < EPTA; k++)
        if (v[k] >= 0) atomicAdd(&dh[v[k] & (CB - 1)], 1);
    __syncthreads();
    int* dp = degPart + blockIdx.x * CB;
    for (int i = t; i < CB; i += BA) dp[i] = dh[i];
}

// per node: deg = sum of nch chunk partials; dinv = rsqrt(deg+1); sx = x*dinv
__global__ __launch_bounds__(256) void k_dinv(const int* __restrict__ gfill1,
                                              const int* __restrict__ degPart,
                                              const float* __restrict__ x,
                                              float* __restrict__ dinv,
                                              float2* __restrict__ sx) {
    int node = blockIdx.x * 256 + threadIdx.x;
    if (node >= N) return;
    int c = node >> LOGCB, i = node & (CB - 1);
    int nch = (min(gfill1[c], CAP1) + ECA - 1) / ECA;
    const int* p = degPart + (size_t)c * MAXCH * CB + i;
    int deg = 0;
    for (int j = 0; j < nch; j++) deg += p[j * CB];
    float di = rsqrtf((float)(deg + 1));
    dinv[node] = di;
    float2 xv = ((const float2*)x)[node];
    sx[node] = make_float2(xv.x * di, xv.y * di);
}

// pure gather engine: stream slotsC, gather vals[src], write msg coalesced.
// No LDS, no barriers, no atomics -> max memory-level parallelism.
__global__ __launch_bounds__(BA) void k_gath(const int* __restrict__ gfill1,
                                             const int* __restrict__ slotsC,
                                             const float2* __restrict__ vals,
                                             float2* __restrict__ msg) {
    int c = blockIdx.x / MAXCH, j = blockIdx.x % MAXCH;
    int fill = min(gfill1[c], CAP1);
    int e0 = j * ECA;
    if (e0 >= fill) return;
    int e1 = min(fill, e0 + ECA);
    int t = threadIdx.x;
    const int* row = slotsC + c * CAP1;
    float2* mrow = msg + (size_t)c * CAP1;
    int v[EPTA];
    int ebase = e0 + t * EPTA;
#pragma unroll
    for (int k = 0; k < EPTA / 4; k++) {
        int idx = ebase + 4 * k;
        if (idx + 3 < e1) {
            *(int4*)(v + 4 * k) = *(const int4*)(row + idx);
        } else {
            for (int jj = 0; jj < 4; jj++) v[4 * k + jj] = (idx + jj < e1) ? row[idx + jj] : -1;
        }
    }
    float2 g[EPTA];
#pragma unroll
    for (int k = 0; k < EPTA; k++) g[k] = (v[k] >= 0) ? vals[v[k] >> LOGCB] : make_float2(0.f, 0.f);
#pragma unroll
    for (int k = 0; k < EPTA; k += 2) {
        int idx = ebase + k;
        if (idx + 1 < e1) {
            *(float4*)(mrow + idx) = make_float4(g[k].x, g[k].y, g[k + 1].x, g[k + 1].y);
        } else if (idx < e1) {
            mrow[idx] = g[k];
        }
    }
}

// pure scatter: stream slotsC + msg (coalesced), LDS accumulate, partials out.
__global__ __launch_bounds__(BA) void k_scat(const int* __restrict__ gfill1,
                                             const int* __restrict__ slotsC,
                                             const float2* __restrict__ msg,
                                             float* __restrict__ partX,
                                             float* __restrict__ partY) {
    __shared__ float aX[CB], aY[CB];
    int c = blockIdx.x / MAXCH, j = blockIdx.x % MAXCH;
    int fill = min(gfill1[c], CAP1);
    int e0 = j * ECA;
    if (e0 >= fill) return;  // uniform per block, before any sync
    int e1 = min(fill, e0 + ECA);
    int t = threadIdx.x;
    for (int i = t; i < CB; i += BA) { aX[i] = 0.f; aY[i] = 0.f; }
    __syncthreads();
    const int* row = slotsC + c * CAP1;
    const float2* mrow = msg + (size_t)c * CAP1;
    int v[EPTA];
    float2 m[EPTA];
    int ebase = e0 + t * EPTA;
#pragma unroll
    for (int k = 0; k < EPTA / 4; k++) {
        int idx = ebase + 4 * k;
        if (idx + 3 < e1) {
            *(int4*)(v + 4 * k) = *(const int4*)(row + idx);
        } else {
            for (int jj = 0; jj < 4; jj++) v[4 * k + jj] = (idx + jj < e1) ? row[idx + jj] : -1;
        }
    }
#pragma unroll
    for (int k = 0; k < EPTA; k += 2) {
        int idx = ebase + k;
        if (idx + 1 < e1) {
            float4 p = *(const float4*)(mrow + idx);
            m[k] = make_float2(p.x, p.y);
            m[k + 1] = make_float2(p.z, p.w);
        } else {
            m[k] = (idx < e1) ? mrow[idx] : make_float2(0.f, 0.f);
            m[k + 1] = make_float2(0.f, 0.f);
        }
    }
#pragma unroll
    for (int k = 0; k < EPTA; k++) {
        if (v[k] >= 0) {
            int d = v[k] & (CB - 1);
            atomicAdd(&aX[d], m[k].x);
            atomicAdd(&aY[d], m[k].y);
        }
    }
    __syncthreads();
    float* px = partX + blockIdx.x * CB;
    float* py = partY + blockIdx.x * CB;
    for (int i = t; i < CB; i += BA) { px[i] = aX[i]; py[i] = aY[i]; }
}

// combine layer1 partials + self, *di, fused MLP; sz = (h@W2)*di
__global__ __launch_bounds__(256) void k_comb1(const int* __restrict__ gfill1,
                                               const float* __restrict__ partX,
                                               const float* __restrict__ partY,
                                               const float* __restrict__ dinv,
                                               const float2* __restrict__ sx,
                                               const float* __restrict__ W1,
                                               const float* __restrict__ b1,
                                               const float* __restrict__ W2,
                                               float2* __restrict__ sz) {
    __shared__ float sW1[32], sb1[16], sW2[32];
    int t = threadIdx.x;
    if (t < 32) sW1[t] = W1[t];
    else if (t < 48) sb1[t - 32] = b1[t - 32];
    else if (t < 80) sW2[t - 48] = W2[t - 48];
    __syncthreads();
    int node = blockIdx.x * 256 + t;
    if (node >= N) return;
    int c = node >> LOGCB, i = node & (CB - 1);
    int nch = (min(gfill1[c], CAP1) + ECA - 1) / ECA;
    const float* px = partX + (size_t)c * MAXCH * CB + i;
    const float* py = partY + (size_t)c * MAXCH * CB + i;
    float ax = 0.f, ay = 0.f;
    for (int j = 0; j < nch; j++) { ax += px[j * CB]; ay += py[j * CB]; }
    float di = dinv[node];
    float2 sv = sx[node];
    float a0 = (ax + sv.x) * di;
    float a1 = (ay + sv.y) * di;
    float z0 = 0.f, z1 = 0.f;
#pragma unroll
    for (int k = 0; k < 16; k++) {
        float h = fmaf(a0, sW1[k], fmaf(a1, sW1[16 + k], sb1[k]));
        h = fmaxf(h, 0.f);
        z0 = fmaf(h, sW2[2 * k + 0], z0);
        z1 = fmaf(h, sW2[2 * k + 1], z1);
    }
    sz[node] = make_float2(z0 * di, z1 * di);
}

// combine layer2 partials + self, *di, + bias, log_softmax
__global__ __launch_bounds__(256) void k_comb2(const int* __restrict__ gfill1,
                                               const float* __restrict__ partX,
                                               const float* __restrict__ partY,
                                               const float* __restrict__ dinv,
                                               const float2* __restrict__ sz,
                                               const float* __restrict__ b2,
                                               float2* __restrict__ out) {
    int node = blockIdx.x * 256 + threadIdx.x;
    if (node >= N) return;
    int c = node >> LOGCB, i = node & (CB - 1);
    int nch = (min(gfill1[c], CAP1) + ECA - 1) / ECA;
    const float* px = partX + (size_t)c * MAXCH * CB + i;
    const float* py = partY + (size_t)c * MAXCH * CB + i;
    float ax = 0.f, ay = 0.f;
    for (int j = 0; j < nch; j++) { ax += px[j * CB]; ay += py[j * CB]; }
    float di = dinv[node];
    float2 sv = sz[node];
    float v0 = fmaf(ax + sv.x, di, b2[0]);
    float v1 = fmaf(ay + sv.y, di, b2[1]);
    float m = fmaxf(v0, v1);
    float lse = m + logf(expf(v0 - m) + expf(v1 - m));
    out[node] = make_float2(v0 - lse, v1 - lse);
}

extern "C" void kernel_launch(void* const* d_in, const int* in_sizes, int n_in,
                              void* d_out, int out_size, void* d_ws, size_t ws_size,
                              hipStream_t stream) {
    const float* x  = (const float*)d_in[0];
    const int*   ei = (const int*)d_in[1];
    const float* W1 = (const float*)d_in[2];
    const float* b1 = (const float*)d_in[3];
    const float* W2 = (const float*)d_in[4];
    const float* b2 = (const float*)d_in[5];

    const int E = in_sizes[1] / 2;
    const int* src = ei;
    const int* dst = ei + E;
    const int GP = (E + EC1 - 1) / EC1;   // 391 pass1 blocks
    const int GB = NC * MAXCH;            // 1764 walk blocks
    const int GN = (N + 255) / 256;       // 391 node blocks

    char* ws = (char*)d_ws;
    size_t off = 0;
    auto alloc = [&](size_t bytes) {
        char* p = ws + off;
        off += (bytes + 511) & ~size_t(511);
        return p;
    };
    int*    gfill1 = (int*)alloc(128 * sizeof(int));
    float*  dinv   = (float*)alloc(N * sizeof(float));
    float2* sx     = (float2*)alloc(N * sizeof(float2));
    float2* sz     = (float2*)alloc(N * sizeof(float2));
    int*    slotsC = (int*)alloc((size_t)NC * CAP1 * sizeof(int));      // 13.7 MB
    float2* msg    = (float2*)alloc((size_t)NC * CAP1 * sizeof(float2)); // 27.4 MB
    float*  partX  = (float*)alloc((size_t)GB * CB * sizeof(float));    // 7.2 MB
    float*  partY  = (float*)alloc((size_t)GB * CB * sizeof(float));    // 7.2 MB
    // degPart aliases partX: deg consumed by k_dinv before k_scat writes partX
    int*    degPart = (int*)partX;

    hipMemsetAsync(gfill1, 0, 128 * sizeof(int), stream);

    k_pass1<<<GP, B1, 0, stream>>>(src, dst, E, gfill1, slotsC);
    k_deg<<<GB, BA, 0, stream>>>(gfill1, slotsC, degPart);
    k_dinv<<<GN, 256, 0, stream>>>(gfill1, degPart, x, dinv, sx);
    k_gath<<<GB, BA, 0, stream>>>(gfill1, slotsC, sx, msg);
    k_scat<<<GB, BA, 0, stream>>>(gfill1, slotsC, msg, partX, partY);
    k_comb1<<<GN, 256, 0, stream>>>(gfill1, partX, partY, dinv, sx, W1, b1, W2, sz);
    k_gath<<<GB, BA, 0, stream>>>(gfill1, slotsC, sz, msg);
    k_scat<<<GB, BA, 0, stream>>>(gfill1, slotsC, msg, partX, partY);
    k_comb2<<<GN, 256, 0, stream>>>(gfill1, partX, partY, dinv, sz, b2, (float2*)d_out);
}